// Round 3
// baseline (441.032 us; speedup 1.0000x reference)
//
#include <hip/hip_runtime.h>
#include <math.h>

// Problem constants
#define BB 2
#define RR 4096
#define NRAY (BB*RR)            // 8192
#define SC 48
#define NSAMP (NRAY*SC)         // 393216
#define CF 32
#define HID 64
#define ODIM 33                 // 1 sigma + 32 rgb
#define PRES 256
#define PLANE_HW (PRES*PRES)    // 65536
#define RAY_START 0.1f
#define RAY_END 2.0f
#define DELTA ((RAY_END-RAY_START)/(SC-1))

// workspace layout (in floats)
#define OFF_PLANES2  ((size_t)0)
#define OFF_DEPTH_C  ((size_t)12582912)                 // 393216
#define OFF_SIGMA_C  (OFF_DEPTH_C + 393216)             // 393216
#define OFF_RGB_C    (OFF_SIGMA_C + 393216)             // 12582912
#define OFF_DEPTH_F  (OFF_RGB_C + 12582912)             // 393216
#define OFF_SIGMA_F  (OFF_DEPTH_F + 393216)             // 393216
#define OFF_RGB_F    (OFF_SIGMA_F + 393216)             // 12582912
#define OFF_MINMAX   (OFF_RGB_F + 12582912)             // 2 uints (+2 pad)
#define OFF_W2T      (OFF_MINMAX + 4)                   // 33*64 floats (w2 transposed)

typedef __attribute__((ext_vector_type(2))) float f2_t;

// packed fp32 FMA: acc.{x,y} += a.{x,y} * b.{x,y}  (one VOP3P inst = 2 FMA)
__device__ __forceinline__ void pk_fma_vv(f2_t& acc, f2_t a, f2_t b) {
    asm("v_pk_fma_f32 %0, %1, %2, %0" : "+v"(acc) : "v"(a), "v"(b));
}
// variant with the (single allowed) scalar operand: b must be wave-uniform
__device__ __forceinline__ void pk_fma_vs(f2_t& acc, f2_t a, f2_t b) {
    asm("v_pk_fma_f32 %0, %1, %2, %0" : "+v"(acc) : "v"(a), "s"(b));
}
// dword of 2 packed bf16 -> f2_t {lo, hi}
__device__ __forceinline__ f2_t bfpair(unsigned int u) {
    union { unsigned int i; float f; } lo, hi;
    lo.i = u << 16;
    hi.i = u & 0xffff0000u;
    f2_t r; r.x = lo.f; r.y = hi.f;
    return r;
}

__device__ __forceinline__ float softplusf(float x) {
    return fmaxf(x, 0.f) + __logf(1.f + __expf(-fabsf(x)));
}
__device__ __forceinline__ float sigact(float o) {
    float r = __builtin_amdgcn_rcpf(1.f + __expf(-o));
    return fmaf(1.002f, r, -0.001f);
}
__device__ __forceinline__ unsigned short f2bf(float f) {
    union { float f; unsigned int u; } v; v.f = f;
    unsigned int r = v.u + 0x7fffu + ((v.u >> 16) & 1u);   // RNE
    return (unsigned short)(r >> 16);
}
__device__ __forceinline__ unsigned int pack2(float lo, float hi) {
    return (unsigned int)f2bf(lo) | ((unsigned int)f2bf(hi) << 16);
}

// ---------------------------------------------------------------------------
// Kernel 1: planes_bf[bp][y][x][c] = bf16(planes[bp][c][y][x]).
// Pure transpose+convert — the w1 GEMM moved into sample_mlp so the gather
// footprint halves (64B/texel instead of 128B). Also: w2t = w2^T.
__global__ __launch_bounds__(256) void precompute2(
    const float* __restrict__ planes, const float* __restrict__ w2,
    unsigned short* __restrict__ planes_bf, float* __restrict__ w2t)
{
    if (blockIdx.x == 0 && threadIdx.x < ODIM) {
        int k = threadIdx.x;
        for (int j = 0; j < HID; ++j) w2t[k * HID + j] = w2[j * ODIM + k];
    }
    int row = blockIdx.x;
    int bp = row >> 8, y = row & 255;
    int x = threadIdx.x;
    const float* src = planes + (size_t)bp * CF * PLANE_HW + (size_t)y * PRES + x;
    unsigned short* dst = planes_bf + ((size_t)bp * PLANE_HW + (size_t)(y << 8) + x) * CF;
    #pragma unroll
    for (int q = 0; q < 4; ++q) {
        uint4 u;
        u.x = pack2(src[(size_t)(q*8+0)*PLANE_HW], src[(size_t)(q*8+1)*PLANE_HW]);
        u.y = pack2(src[(size_t)(q*8+2)*PLANE_HW], src[(size_t)(q*8+3)*PLANE_HW]);
        u.z = pack2(src[(size_t)(q*8+4)*PLANE_HW], src[(size_t)(q*8+5)*PLANE_HW]);
        u.w = pack2(src[(size_t)(q*8+6)*PLANE_HW], src[(size_t)(q*8+7)*PLANE_HW]);
        ((uint4*)dst)[q] = u;
    }
}

// ---------------------------------------------------------------------------
// Kernel 2 (R15): raw 32-ch bf16 gather + in-kernel GEMM1/GEMM2, one lane per
// sample. R13/R14 root cause: allocator pinned 64 VGPR (8 waves/EU target)
// and spilled the fa+h2 overlap (~123 MB scratch writes). Fix: stage fa in
// LDS (per-thread scratch, 2-way bank aliasing = free, no barrier). This
// (a) removes the fa/h2 register overlap (peak live ~75), and (b) the 32 KB
// LDS block caps occupancy at 5 waves/SIMD so the VGPR budget rises to ~96
// — demand fits, no spill.
__global__ __launch_bounds__(256) void sample_mlp(
    const unsigned short* __restrict__ planes_bf,
    const float* __restrict__ depths_in,   // fine pass
    const float* __restrict__ noise,       // coarse pass
    float* __restrict__ depth_out,         // coarse pass
    const float* __restrict__ origins,
    const float* __restrict__ dirs,
    const float* __restrict__ w1,
    const float* __restrict__ b1,
    const float* __restrict__ w2t, const float* __restrict__ b2,
    float* __restrict__ sigma_out, float* __restrict__ rgb_out,
    int coarse)
{
    __shared__ f2_t s_fa[16][256];   // 32 KB; lane-private columns, no barrier
    int tid = threadIdx.x;
    int sample = blockIdx.x * 256 + tid;
    int ray = sample / SC;
    int b = ray >> 12;

    float depth;
    if (coarse) {
        int s = sample - ray * SC;
        depth = RAY_START + (float)s * DELTA + noise[sample] * DELTA;
        depth_out[sample] = depth;
    } else {
        depth = depths_in[sample];
    }

    float ox = origins[ray*3+0], oy = origins[ray*3+1], oz = origins[ray*3+2];
    float dx = dirs[ray*3+0],    dy = dirs[ray*3+1],    dz = dirs[ray*3+2];
    float cx = (ox + depth*dx) * 0.5f;
    float cy = (oy + depth*dy) * 0.5f;
    float cz = (oz + depth*dz) * 0.5f;

    // interpolated raw features (32 ch as 16 packed pairs)
    f2_t fa[16];
    #pragma unroll
    for (int j = 0; j < 16; ++j) fa[j] = (f2_t){0.f, 0.f};

    #pragma unroll
    for (int p = 0; p < 3; ++p) {
        float gx = (p == 0) ? cx : (p == 1) ? cy : cz;
        float gy = (p == 0) ? cy : (p == 1) ? cz : cx;
        float x = fmaf(gx, 128.f, 127.5f);
        float y = fmaf(gy, 128.f, 127.5f);
        float x0f = floorf(x), y0f = floorf(y);
        float wx1 = x - x0f, wy1 = y - y0f;
        int x0 = (int)x0f, y0 = (int)y0f;
        const unsigned short* pb = planes_bf + (size_t)(b*3 + p) * PLANE_HW * CF;
        #pragma unroll
        for (int cyi = 0; cyi < 2; ++cyi) {
            #pragma unroll
            for (int cxi = 0; cxi < 2; ++cxi) {
                int xi = x0 + cxi, yi = y0 + cyi;
                float wgt = ((cyi ? wy1 : 1.f - wy1) * (cxi ? wx1 : 1.f - wx1)) * (1.f/3.f);
                if (xi < 0 || xi > 255 || yi < 0 || yi > 255) wgt = 0.f;
                int xc = min(max(xi, 0), 255), yc = min(max(yi, 0), 255);
                const uint4* tp = (const uint4*)(pb + (size_t)((yc << 8) + xc) * CF);
                uint4 v0 = tp[0], v1 = tp[1], v2 = tp[2], v3 = tp[3];
                f2_t wp2; wp2.x = wgt; wp2.y = wgt;
                pk_fma_vv(fa[0],  bfpair(v0.x), wp2);
                pk_fma_vv(fa[1],  bfpair(v0.y), wp2);
                pk_fma_vv(fa[2],  bfpair(v0.z), wp2);
                pk_fma_vv(fa[3],  bfpair(v0.w), wp2);
                pk_fma_vv(fa[4],  bfpair(v1.x), wp2);
                pk_fma_vv(fa[5],  bfpair(v1.y), wp2);
                pk_fma_vv(fa[6],  bfpair(v1.z), wp2);
                pk_fma_vv(fa[7],  bfpair(v1.w), wp2);
                pk_fma_vv(fa[8],  bfpair(v2.x), wp2);
                pk_fma_vv(fa[9],  bfpair(v2.y), wp2);
                pk_fma_vv(fa[10], bfpair(v2.z), wp2);
                pk_fma_vv(fa[11], bfpair(v2.w), wp2);
                pk_fma_vv(fa[12], bfpair(v3.x), wp2);
                pk_fma_vv(fa[13], bfpair(v3.y), wp2);
                pk_fma_vv(fa[14], bfpair(v3.z), wp2);
                pk_fma_vv(fa[15], bfpair(v3.w), wp2);
            }
        }
    }

    // park fa in LDS so its 32 regs die before h2 goes live
    #pragma unroll
    for (int j = 0; j < 16; ++j) s_fa[j][tid] = fa[j];

    // GEMM1: h[64] = fa[32] @ w1[32][64] + b1  (w1 rows wave-uniform -> scalar operand)
    f2_t h2[32];
    const f2_t* b1p = (const f2_t*)b1;
    #pragma unroll
    for (int j = 0; j < 32; ++j) h2[j] = b1p[j];
    #pragma unroll
    for (int c2 = 0; c2 < 16; ++c2) {
        f2_t fp = s_fa[c2][tid];
        f2_t fca; fca.x = fp.x; fca.y = fp.x;
        const f2_t* wpa = (const f2_t*)(w1 + (2*c2) * HID);
        #pragma unroll
        for (int j = 0; j < 32; ++j) pk_fma_vs(h2[j], fca, wpa[j]);
        f2_t fcb; fcb.x = fp.y; fcb.y = fp.y;
        const f2_t* wpb = (const f2_t*)(w1 + (2*c2+1) * HID);
        #pragma unroll
        for (int j = 0; j < 32; ++j) pk_fma_vs(h2[j], fcb, wpb[j]);
    }
    #pragma unroll
    for (int j = 0; j < 32; ++j) {
        h2[j].x = softplusf(h2[j].x);
        h2[j].y = softplusf(h2[j].y);
    }

    // GEMM2: o[33] = h @ w2 + b2, streamed to output (o never fully live)
    {
        const f2_t* wp = (const f2_t*)w2t;
        f2_t acc = (f2_t){0.f, 0.f};
        #pragma unroll
        for (int j = 0; j < 32; ++j) pk_fma_vs(acc, h2[j], wp[j]);
        sigma_out[sample] = acc.x + acc.y + b2[0];
    }
    float4* ro = (float4*)(rgb_out + (size_t)sample * 32);
    #pragma unroll
    for (int q = 0; q < 8; ++q) {
        float4 v;
        #pragma unroll
        for (int t = 0; t < 4; ++t) {
            int k = 1 + q*4 + t;
            const f2_t* wp = (const f2_t*)(w2t + k * HID);
            f2_t acc = (f2_t){0.f, 0.f};
            #pragma unroll
            for (int j = 0; j < 32; ++j) pk_fma_vs(acc, h2[j], wp[j]);
            (&v.x)[t] = sigact(acc.x + acc.y + b2[k]);
        }
        ro[q] = v;
    }
}

// ---------------------------------------------------------------------------
// Kernel 3: importance sampling, one wave per ray; block-level minmax to
// scratch (bmin/bmax staged in rgb_f, overwritten later by the fine pass).
__global__ __launch_bounds__(256) void importance_kernel(
    const float* __restrict__ depth_c, const float* __restrict__ sigma_c,
    const float* __restrict__ noise_imp, float* __restrict__ depth_f,
    float* __restrict__ bmin, float* __restrict__ bmax)
{
    __shared__ float s_cdf[4][46];
    __shared__ float s_bins[4][47];
    __shared__ float s_red[8];
    int wave = threadIdx.x >> 6, lane = threadIdx.x & 63;
    int ray = blockIdx.x * 4 + wave;

    const float* d  = depth_c + (size_t)ray * SC;
    const float* sg = sigma_c + (size_t)ray * SC;
    float dval = (lane < SC) ? d[lane] : 0.f;
    float sval = (lane < SC) ? sg[lane] : 0.f;
    float dnext = __shfl_down(dval, 1);
    float snext = __shfl_down(sval, 1);

    float a = 0.f;
    if (lane < SC-1) {
        float dens = softplusf(0.5f * (sval + snext) - 1.f);
        a = 1.f - expf(-dens * (dnext - dval));
    }
    float f = (lane < SC-1) ? (1.f - a + 1e-10f) : 1.f;
    float incl = f;
    #pragma unroll
    for (int off = 1; off < 64; off <<= 1) {
        float t = __shfl_up(incl, off);
        if (lane >= off) incl *= t;
    }
    float T = (lane == 0) ? 1.f : __shfl_up(incl, 1);
    float w = a * T;
    float wm1 = __shfl_up(w, 1);
    float wp1 = __shfl_down(w, 1);
    float wn = 0.5f * (fmaxf(wm1, w) + fmaxf(w, wp1)) + 0.01f + 1e-5f;
    float g = (lane >= 1 && lane <= 45) ? wn : 0.f;
    float incl2 = g;
    #pragma unroll
    for (int off = 1; off < 64; off <<= 1) {
        float t = __shfl_up(incl2, off);
        if (lane >= off) incl2 += t;
    }
    float sum = __shfl(incl2, 45);
    if (lane == 0) s_cdf[wave][0] = 0.f;
    else if (lane <= 45) s_cdf[wave][lane] = incl2 / sum;
    if (lane < SC-1) s_bins[wave][lane] = 0.5f * (dval + dnext);
    __syncthreads();

    float fmn = 1e30f, fmx = -1e30f;
    if (lane < SC) {
        float u = noise_imp[(size_t)ray * SC + lane];
        int inds = 0;
        #pragma unroll
        for (int t = 0; t < 46; ++t) inds += (s_cdf[wave][t] <= u) ? 1 : 0;
        int below = max(inds - 1, 0), above = min(inds, 45);
        float cb = s_cdf[wave][below], ca = s_cdf[wave][above];
        float bb = s_bins[wave][below], ba = s_bins[wave][above];
        float den = (ca - cb < 1e-5f) ? 1.f : (ca - cb);
        float s = bb + (u - cb) / den * (ba - bb);
        depth_f[(size_t)ray * SC + lane] = s;
        fmn = s; fmx = s;
    }
    float d0 = __shfl(dval, 0), dlast = __shfl(dval, SC-1);
    fmn = fminf(fmn, d0); fmx = fmaxf(fmx, dlast);
    #pragma unroll
    for (int off = 32; off >= 1; off >>= 1) {
        fmn = fminf(fmn, __shfl_xor(fmn, off));
        fmx = fmaxf(fmx, __shfl_xor(fmx, off));
    }
    if (lane == 0) { s_red[wave] = fmn; s_red[4 + wave] = fmx; }
    __syncthreads();
    if (threadIdx.x == 0) {
        bmin[blockIdx.x] = fminf(fminf(s_red[0], s_red[1]), fminf(s_red[2], s_red[3]));
        bmax[blockIdx.x] = fmaxf(fmaxf(s_red[4], s_red[5]), fmaxf(s_red[6], s_red[7]));
    }
}

// ---------------------------------------------------------------------------
// Kernel 3b: fold 2048 per-block (min,max) pairs into minmax[0..1]. 1 block.
__global__ __launch_bounds__(1024) void reduce_minmax(
    const float* __restrict__ bmin, const float* __restrict__ bmax,
    unsigned int* __restrict__ minmax)
{
    int tid = threadIdx.x;
    float mn = fminf(bmin[tid], bmin[tid + 1024]);
    float mx = fmaxf(bmax[tid], bmax[tid + 1024]);
    #pragma unroll
    for (int off = 32; off >= 1; off >>= 1) {
        mn = fminf(mn, __shfl_xor(mn, off));
        mx = fmaxf(mx, __shfl_xor(mx, off));
    }
    __shared__ float smn[16], smx[16];
    int wv = tid >> 6;
    if ((tid & 63) == 0) { smn[wv] = mn; smx[wv] = mx; }
    __syncthreads();
    if (tid == 0) {
        float m = smn[0], M = smx[0];
        #pragma unroll
        for (int i = 1; i < 16; ++i) { m = fminf(m, smn[i]); M = fmaxf(M, smx[i]); }
        minmax[0] = __float_as_uint(m);
        minmax[1] = __float_as_uint(M);
    }
}

// ---------------------------------------------------------------------------
// Kernel 4: merge coarse+fine (stable rank sort of 96), final ray-march.
// (unchanged known-passing serial-cumprod version)
__global__ __launch_bounds__(256) void final_march(
    const float* __restrict__ depth_c, const float* __restrict__ sigma_c,
    const float* __restrict__ rgb_c,
    const float* __restrict__ depth_f, const float* __restrict__ sigma_f,
    const float* __restrict__ rgb_f,
    const unsigned int* __restrict__ minmax,
    float* __restrict__ out)
{
    __shared__ float dall[4][96];
    __shared__ float sall[4][96];
    __shared__ float dsrt[4][96];
    __shared__ float ssrt[4][96];
    __shared__ int   perm[4][96];
    __shared__ float al[4][96];

    int wid = threadIdx.x >> 6, lane = threadIdx.x & 63;
    int ray = blockIdx.x * 4 + wid;

    for (int j = lane; j < 96; j += 64) {
        float dv, sv;
        if (j < 48) { dv = depth_c[(size_t)ray*48 + j]; sv = sigma_c[(size_t)ray*48 + j]; }
        else        { dv = depth_f[(size_t)ray*48 + j-48]; sv = sigma_f[(size_t)ray*48 + j-48]; }
        dall[wid][j] = dv; sall[wid][j] = sv;
    }
    __syncthreads();
    for (int j = lane; j < 96; j += 64) {
        float dj = dall[wid][j];
        int rank = 0;
        for (int k = 0; k < 96; ++k) {
            float dk = dall[wid][k];
            rank += (dk < dj || (dk == dj && k < j)) ? 1 : 0;
        }
        dsrt[wid][rank] = dj;
        ssrt[wid][rank] = sall[wid][j];
        perm[wid][rank] = j;
    }
    __syncthreads();
    for (int i = lane; i < 95; i += 64) {
        float dlt = dsrt[wid][i+1] - dsrt[wid][i];
        float dens = softplusf(0.5f * (ssrt[wid][i] + ssrt[wid][i+1]) - 1.f);
        al[wid][i] = 1.f - expf(-dens * dlt);
    }
    __syncthreads();
    if (lane == 0) {
        float T = 1.f, wsum = 0.f, dsum = 0.f;
        for (int i = 0; i < 95; ++i) {
            float a = al[wid][i];
            float wloc = a * T;
            T *= 1.f - a + 1e-10f;
            al[wid][i] = wloc;
            wsum += wloc;
            dsum += wloc * 0.5f * (dsrt[wid][i] + dsrt[wid][i+1]);
        }
        float depth = dsum / wsum;
        if (isnan(depth)) depth = INFINITY;
        float gmn = __uint_as_float(minmax[0]);
        float gmx = __uint_as_float(minmax[1]);
        depth = fminf(fmaxf(depth, gmn), gmx);
        out[262144 + ray] = depth;
        out[270336 + ray] = wsum;
        out[278528 + ray] = T;
    }
    __syncthreads();
    int k = lane & 31, half = lane >> 5;
    int i0 = half * 48, i1 = half ? 95 : 48;
    const float* rc = rgb_c + (size_t)ray * 48 * 32;
    const float* rf = rgb_f + (size_t)ray * 48 * 32;
    float acc = 0.f;
    int j0 = perm[wid][i0];
    float cur = (j0 < 48) ? rc[j0*32 + k] : rf[(j0-48)*32 + k];
    for (int i = i0; i < i1; ++i) {
        int jn = perm[wid][i+1];
        float nxt = (jn < 48) ? rc[jn*32 + k] : rf[(jn-48)*32 + k];
        acc += al[wid][i] * (cur + nxt);
        cur = nxt;
    }
    acc *= 0.5f;
    acc += __shfl_xor(acc, 32);
    if (half == 0) out[(size_t)ray * 32 + k] = acc * 2.f - 1.f;
}

// ---------------------------------------------------------------------------
extern "C" void kernel_launch(void* const* d_in, const int* in_sizes, int n_in,
                              void* d_out, int out_size, void* d_ws, size_t ws_size,
                              hipStream_t stream) {
    const float* planes      = (const float*)d_in[0];
    const float* origins     = (const float*)d_in[1];
    const float* dirs        = (const float*)d_in[2];
    const float* w1          = (const float*)d_in[3];
    const float* b1          = (const float*)d_in[4];
    const float* w2          = (const float*)d_in[5];
    const float* b2          = (const float*)d_in[6];
    const float* noise_strat = (const float*)d_in[7];
    const float* noise_imp   = (const float*)d_in[8];
    float* out = (float*)d_out;
    float* ws  = (float*)d_ws;

    unsigned short* planes_bf = (unsigned short*)(ws + OFF_PLANES2);
    float* depth_c = ws + OFF_DEPTH_C;
    float* sigma_c = ws + OFF_SIGMA_C;
    float* rgb_c   = ws + OFF_RGB_C;
    float* depth_f = ws + OFF_DEPTH_F;
    float* sigma_f = ws + OFF_SIGMA_F;
    float* rgb_f   = ws + OFF_RGB_F;
    unsigned int* minmax = (unsigned int*)(ws + OFF_MINMAX);
    float* w2t = ws + OFF_W2T;
    // per-block minmax scratch: staged in rgb_f (overwritten later by fine pass)
    float* bmin = rgb_f;
    float* bmax = rgb_f + 2048;

    precompute2<<<1536, 256, 0, stream>>>(planes, w2, planes_bf, w2t);
    sample_mlp<<<NSAMP/256, 256, 0, stream>>>(planes_bf, nullptr, noise_strat, depth_c,
                                              origins, dirs, w1, b1, w2t, b2,
                                              sigma_c, rgb_c, 1);
    importance_kernel<<<NRAY/4, 256, 0, stream>>>(depth_c, sigma_c, noise_imp,
                                                  depth_f, bmin, bmax);
    reduce_minmax<<<1, 1024, 0, stream>>>(bmin, bmax, minmax);
    sample_mlp<<<NSAMP/256, 256, 0, stream>>>(planes_bf, depth_f, nullptr, nullptr,
                                              origins, dirs, w1, b1, w2t, b2,
                                              sigma_f, rgb_f, 0);
    final_march<<<NRAY/4, 256, 0, stream>>>(depth_c, sigma_c, rgb_c,
                                            depth_f, sigma_f, rgb_f, minmax, out);
}

// Round 4
// 404.354 us; speedup vs baseline: 1.0907x; 1.0907x over previous
//
#include <hip/hip_runtime.h>
#include <math.h>

// Problem constants
#define BB 2
#define RR 4096
#define NRAY (BB*RR)            // 8192
#define SC 48
#define NSAMP (NRAY*SC)         // 393216
#define CF 32
#define HID 64
#define ODIM 33                 // 1 sigma + 32 rgb
#define PRES 256
#define PLANE_HW (PRES*PRES)    // 65536
#define RAY_START 0.1f
#define RAY_END 2.0f
#define DELTA ((RAY_END-RAY_START)/(SC-1))

// workspace layout (in floats)
#define OFF_PLANES2  ((size_t)0)
#define OFF_DEPTH_C  ((size_t)12582912)                 // 393216
#define OFF_SIGMA_C  (OFF_DEPTH_C + 393216)             // 393216
#define OFF_RGB_C    (OFF_SIGMA_C + 393216)             // 12582912
#define OFF_DEPTH_F  (OFF_RGB_C + 12582912)             // 393216
#define OFF_SIGMA_F  (OFF_DEPTH_F + 393216)             // 393216
#define OFF_RGB_F    (OFF_SIGMA_F + 393216)             // 12582912
#define OFF_MINMAX   (OFF_RGB_F + 12582912)             // 2 uints (+2 pad)
#define OFF_W2T      (OFF_MINMAX + 4)                   // 33*64 floats (w2 transposed)

typedef __attribute__((ext_vector_type(2))) float f2_t;

// packed fp32 FMA: acc.{x,y} += a.{x,y} * b.{x,y}  (one VOP3P inst = 2 FMA)
__device__ __forceinline__ void pk_fma_vv(f2_t& acc, f2_t a, f2_t b) {
    asm("v_pk_fma_f32 %0, %1, %2, %0" : "+v"(acc) : "v"(a), "v"(b));
}
// variant with the (single allowed) scalar operand: b must be wave-uniform
__device__ __forceinline__ void pk_fma_vs(f2_t& acc, f2_t a, f2_t b) {
    asm("v_pk_fma_f32 %0, %1, %2, %0" : "+v"(acc) : "v"(a), "s"(b));
}
// dword of 2 packed bf16 -> f2_t {lo, hi}
__device__ __forceinline__ f2_t bfpair(unsigned int u) {
    union { unsigned int i; float f; } lo, hi;
    lo.i = u << 16;
    hi.i = u & 0xffff0000u;
    f2_t r; r.x = lo.f; r.y = hi.f;
    return r;
}

__device__ __forceinline__ float softplusf(float x) {
    return fmaxf(x, 0.f) + __logf(1.f + __expf(-fabsf(x)));
}
__device__ __forceinline__ float sigact(float o) {
    float r = __builtin_amdgcn_rcpf(1.f + __expf(-o));
    return fmaf(1.002f, r, -0.001f);
}
__device__ __forceinline__ unsigned short f2bf(float f) {
    union { float f; unsigned int u; } v; v.f = f;
    unsigned int r = v.u + 0x7fffu + ((v.u >> 16) & 1u);   // RNE
    return (unsigned short)(r >> 16);
}
__device__ __forceinline__ unsigned int pack2(float lo, float hi) {
    return (unsigned int)f2bf(lo) | ((unsigned int)f2bf(hi) << 16);
}

// ---------------------------------------------------------------------------
// Kernel 1: planes_bf[bp][y][x][c] = bf16(planes[bp][c][y][x]).
// Pure transpose+convert. Also: w2t = w2^T.
__global__ __launch_bounds__(256) void precompute2(
    const float* __restrict__ planes, const float* __restrict__ w2,
    unsigned short* __restrict__ planes_bf, float* __restrict__ w2t)
{
    if (blockIdx.x == 0 && threadIdx.x < ODIM) {
        int k = threadIdx.x;
        for (int j = 0; j < HID; ++j) w2t[k * HID + j] = w2[j * ODIM + k];
    }
    int row = blockIdx.x;
    int bp = row >> 8, y = row & 255;
    int x = threadIdx.x;
    const float* src = planes + (size_t)bp * CF * PLANE_HW + (size_t)y * PRES + x;
    unsigned short* dst = planes_bf + ((size_t)bp * PLANE_HW + (size_t)(y << 8) + x) * CF;
    #pragma unroll
    for (int q = 0; q < 4; ++q) {
        uint4 u;
        u.x = pack2(src[(size_t)(q*8+0)*PLANE_HW], src[(size_t)(q*8+1)*PLANE_HW]);
        u.y = pack2(src[(size_t)(q*8+2)*PLANE_HW], src[(size_t)(q*8+3)*PLANE_HW]);
        u.z = pack2(src[(size_t)(q*8+4)*PLANE_HW], src[(size_t)(q*8+5)*PLANE_HW]);
        u.w = pack2(src[(size_t)(q*8+6)*PLANE_HW], src[(size_t)(q*8+7)*PLANE_HW]);
        ((uint4*)dst)[q] = u;
    }
}

// ---------------------------------------------------------------------------
// Kernel 2 (R16): R12's proven two-wave-per-sample register shape + R13's raw
// 32-ch gather. Wave half h gathers FEATURE channels [16h,16h+16) (32B/corner
// = 2x16B requests -> 48 req/sample vs R12's 96), exchanges halves via LDS,
// then computes HIDDEN channels [32h,32h+32) (h2[16] = 32 VGPRs -> fits the
// 64-reg budget like R12; R13-R15's one-lane h2[32] structure spilled ~126MB
// at the pinned 64-VGPR allocation, 3 rounds of evidence).
__global__ __launch_bounds__(256, 3) void sample_mlp(
    const unsigned short* __restrict__ planes_bf,
    const float* __restrict__ depths_in,   // fine pass
    const float* __restrict__ noise,       // coarse pass
    float* __restrict__ depth_out,         // coarse pass
    const float* __restrict__ origins,
    const float* __restrict__ dirs,
    const float* __restrict__ w1,
    const float* __restrict__ b1,
    const float* __restrict__ w2t, const float* __restrict__ b2,
    float* __restrict__ sigma_out, float* __restrict__ rgb_out,
    int coarse)
{
    __shared__ __align__(8) float s_buf[2][64][34];   // 17408 B; feat-exchange then o-partials

    int lane = threadIdx.x & 63;
    int wv = threadIdx.x >> 6;
    int halfu = __builtin_amdgcn_readfirstlane(wv & 1);   // SGPR: keeps weight loads scalar
    int pairu = __builtin_amdgcn_readfirstlane(wv >> 1);
    int sample = blockIdx.x * 128 + pairu * 64 + lane;
    int ray = sample / SC;
    int b = ray >> 12;

    float depth;
    if (coarse) {
        int s = sample - ray * SC;
        depth = RAY_START + (float)s * DELTA + noise[sample] * DELTA;
        if (halfu == 0) depth_out[sample] = depth;
    } else {
        depth = depths_in[sample];
    }

    float ox = origins[ray*3+0], oy = origins[ray*3+1], oz = origins[ray*3+2];
    float dx = dirs[ray*3+0],    dy = dirs[ray*3+1],    dz = dirs[ray*3+2];
    float cx = (ox + depth*dx) * 0.5f;
    float cy = (oy + depth*dy) * 0.5f;
    float cz = (oz + depth*dz) * 0.5f;

    // gather own 16 feature channels (8 packed pairs), 32B/corner
    f2_t fa[8];
    #pragma unroll
    for (int j = 0; j < 8; ++j) fa[j] = (f2_t){0.f, 0.f};

    #pragma unroll
    for (int p = 0; p < 3; ++p) {
        float gx = (p == 0) ? cx : (p == 1) ? cy : cz;
        float gy = (p == 0) ? cy : (p == 1) ? cz : cx;
        float x = fmaf(gx, 128.f, 127.5f);
        float y = fmaf(gy, 128.f, 127.5f);
        float x0f = floorf(x), y0f = floorf(y);
        float wx1 = x - x0f, wy1 = y - y0f;
        int x0 = (int)x0f, y0 = (int)y0f;
        const unsigned short* pb = planes_bf + (size_t)(b*3 + p) * PLANE_HW * CF + halfu * 16;
        #pragma unroll
        for (int cyi = 0; cyi < 2; ++cyi) {
            #pragma unroll
            for (int cxi = 0; cxi < 2; ++cxi) {
                int xi = x0 + cxi, yi = y0 + cyi;
                float wgt = ((cyi ? wy1 : 1.f - wy1) * (cxi ? wx1 : 1.f - wx1)) * (1.f/3.f);
                if (xi < 0 || xi > 255 || yi < 0 || yi > 255) wgt = 0.f;
                int xc = min(max(xi, 0), 255), yc = min(max(yi, 0), 255);
                const uint4* tp = (const uint4*)(pb + (size_t)((yc << 8) + xc) * CF);
                uint4 v0 = tp[0], v1 = tp[1];
                f2_t wp2; wp2.x = wgt; wp2.y = wgt;
                pk_fma_vv(fa[0], bfpair(v0.x), wp2);
                pk_fma_vv(fa[1], bfpair(v0.y), wp2);
                pk_fma_vv(fa[2], bfpair(v0.z), wp2);
                pk_fma_vv(fa[3], bfpair(v0.w), wp2);
                pk_fma_vv(fa[4], bfpair(v1.x), wp2);
                pk_fma_vv(fa[5], bfpair(v1.y), wp2);
                pk_fma_vv(fa[6], bfpair(v1.z), wp2);
                pk_fma_vv(fa[7], bfpair(v1.w), wp2);
            }
        }
    }

    // exchange: own half -> LDS cols [16h,16h+16)
    {
        f2_t* dstp = (f2_t*)&s_buf[pairu][lane][0];
        #pragma unroll
        for (int j = 0; j < 8; ++j) dstp[halfu*8 + j] = fa[j];
    }
    __syncthreads();

    // GEMM1: h[32h..32h+32) = sum_c f_c * w1[c][32h+..]; own channels from
    // regs, partner's from LDS. w1 rows wave-uniform -> scalar operand.
    f2_t h2[16];
    const f2_t* b1p = (const f2_t*)(b1 + halfu * 32);
    #pragma unroll
    for (int j = 0; j < 16; ++j) h2[j] = b1p[j];

    #pragma unroll
    for (int cc = 0; cc < 8; ++cc) {       // own: channels 16h+2cc, 16h+2cc+1
        f2_t fp = fa[cc];
        const f2_t* wpa = (const f2_t*)(w1 + (16*halfu + 2*cc) * HID + halfu * 32);
        f2_t fca; fca.x = fp.x; fca.y = fp.x;
        #pragma unroll
        for (int j = 0; j < 16; ++j) pk_fma_vs(h2[j], fca, wpa[j]);
        const f2_t* wpb = wpa + HID/2;
        f2_t fcb; fcb.x = fp.y; fcb.y = fp.y;
        #pragma unroll
        for (int j = 0; j < 16; ++j) pk_fma_vs(h2[j], fcb, wpb[j]);
    }
    {
        const f2_t* part = (const f2_t*)&s_buf[pairu][lane][0];
        #pragma unroll
        for (int cc = 0; cc < 8; ++cc) {   // partner: channels 16(1-h)+2cc, +1
            f2_t fp = part[(1-halfu)*8 + cc];
            const f2_t* wpa = (const f2_t*)(w1 + (16*(1-halfu) + 2*cc) * HID + halfu * 32);
            f2_t fca; fca.x = fp.x; fca.y = fp.x;
            #pragma unroll
            for (int j = 0; j < 16; ++j) pk_fma_vs(h2[j], fca, wpa[j]);
            const f2_t* wpb = wpa + HID/2;
            f2_t fcb; fcb.x = fp.y; fcb.y = fp.y;
            #pragma unroll
            for (int j = 0; j < 16; ++j) pk_fma_vs(h2[j], fcb, wpb[j]);
        }
    }
    #pragma unroll
    for (int j = 0; j < 16; ++j) {
        h2[j].x = softplusf(h2[j].x);
        h2[j].y = softplusf(h2[j].y);
    }

    // partial GEMM2 over own 32 hidden channels; w2t row halves via SGPR offset.
    float o[ODIM + 1];   // pad to 34 for f2 LDS traffic
    const f2_t* wbase = (const f2_t*)(w2t + halfu * 32);
    #pragma unroll
    for (int k = 0; k < ODIM; ++k) {
        const f2_t* wp = wbase + k * (HID/2);
        f2_t acc = (f2_t){0.f, 0.f};
        #pragma unroll
        for (int j = 0; j < 16; ++j) pk_fma_vs(acc, h2[j], wp[j]);
        o[k] = acc.x + acc.y;
    }
    o[ODIM] = 0.f;

    __syncthreads();   // everyone done reading features; s_buf reused for o-partials
    if (halfu) {
        f2_t* dstp = (f2_t*)&s_buf[pairu][lane][0];
        #pragma unroll
        for (int j = 0; j < 17; ++j) {
            f2_t v; v.x = o[2*j]; v.y = o[2*j+1];
            dstp[j] = v;
        }
    }
    __syncthreads();
    if (!halfu) {
        const f2_t* srcp = (const f2_t*)&s_buf[pairu][lane][0];
        #pragma unroll
        for (int j = 0; j < 17; ++j) {
            f2_t v = srcp[j];
            o[2*j]   += v.x;
            o[2*j+1] += v.y;
        }
        #pragma unroll
        for (int k = 0; k < ODIM; ++k) o[k] += b2[k];

        sigma_out[sample] = o[0];
        float4* ro = (float4*)(rgb_out + (size_t)sample * 32);
        #pragma unroll
        for (int q = 0; q < 8; ++q) {
            float4 v;
            v.x = sigact(o[1 + q*4 + 0]);
            v.y = sigact(o[1 + q*4 + 1]);
            v.z = sigact(o[1 + q*4 + 2]);
            v.w = sigact(o[1 + q*4 + 3]);
            ro[q] = v;
        }
    }
}

// ---------------------------------------------------------------------------
// Kernel 3: importance sampling, one wave per ray; block-level minmax to
// scratch (bmin/bmax staged in rgb_f, overwritten later by the fine pass).
__global__ __launch_bounds__(256) void importance_kernel(
    const float* __restrict__ depth_c, const float* __restrict__ sigma_c,
    const float* __restrict__ noise_imp, float* __restrict__ depth_f,
    float* __restrict__ bmin, float* __restrict__ bmax)
{
    __shared__ float s_cdf[4][46];
    __shared__ float s_bins[4][47];
    __shared__ float s_red[8];
    int wave = threadIdx.x >> 6, lane = threadIdx.x & 63;
    int ray = blockIdx.x * 4 + wave;

    const float* d  = depth_c + (size_t)ray * SC;
    const float* sg = sigma_c + (size_t)ray * SC;
    float dval = (lane < SC) ? d[lane] : 0.f;
    float sval = (lane < SC) ? sg[lane] : 0.f;
    float dnext = __shfl_down(dval, 1);
    float snext = __shfl_down(sval, 1);

    float a = 0.f;
    if (lane < SC-1) {
        float dens = softplusf(0.5f * (sval + snext) - 1.f);
        a = 1.f - expf(-dens * (dnext - dval));
    }
    float f = (lane < SC-1) ? (1.f - a + 1e-10f) : 1.f;
    float incl = f;
    #pragma unroll
    for (int off = 1; off < 64; off <<= 1) {
        float t = __shfl_up(incl, off);
        if (lane >= off) incl *= t;
    }
    float T = (lane == 0) ? 1.f : __shfl_up(incl, 1);
    float w = a * T;
    float wm1 = __shfl_up(w, 1);
    float wp1 = __shfl_down(w, 1);
    float wn = 0.5f * (fmaxf(wm1, w) + fmaxf(w, wp1)) + 0.01f + 1e-5f;
    float g = (lane >= 1 && lane <= 45) ? wn : 0.f;
    float incl2 = g;
    #pragma unroll
    for (int off = 1; off < 64; off <<= 1) {
        float t = __shfl_up(incl2, off);
        if (lane >= off) incl2 += t;
    }
    float sum = __shfl(incl2, 45);
    if (lane == 0) s_cdf[wave][0] = 0.f;
    else if (lane <= 45) s_cdf[wave][lane] = incl2 / sum;
    if (lane < SC-1) s_bins[wave][lane] = 0.5f * (dval + dnext);
    __syncthreads();

    float fmn = 1e30f, fmx = -1e30f;
    if (lane < SC) {
        float u = noise_imp[(size_t)ray * SC + lane];
        int inds = 0;
        #pragma unroll
        for (int t = 0; t < 46; ++t) inds += (s_cdf[wave][t] <= u) ? 1 : 0;
        int below = max(inds - 1, 0), above = min(inds, 45);
        float cb = s_cdf[wave][below], ca = s_cdf[wave][above];
        float bb = s_bins[wave][below], ba = s_bins[wave][above];
        float den = (ca - cb < 1e-5f) ? 1.f : (ca - cb);
        float s = bb + (u - cb) / den * (ba - bb);
        depth_f[(size_t)ray * SC + lane] = s;
        fmn = s; fmx = s;
    }
    float d0 = __shfl(dval, 0), dlast = __shfl(dval, SC-1);
    fmn = fminf(fmn, d0); fmx = fmaxf(fmx, dlast);
    #pragma unroll
    for (int off = 32; off >= 1; off >>= 1) {
        fmn = fminf(fmn, __shfl_xor(fmn, off));
        fmx = fmaxf(fmx, __shfl_xor(fmx, off));
    }
    if (lane == 0) { s_red[wave] = fmn; s_red[4 + wave] = fmx; }
    __syncthreads();
    if (threadIdx.x == 0) {
        bmin[blockIdx.x] = fminf(fminf(s_red[0], s_red[1]), fminf(s_red[2], s_red[3]));
        bmax[blockIdx.x] = fmaxf(fmaxf(s_red[4], s_red[5]), fmaxf(s_red[6], s_red[7]));
    }
}

// ---------------------------------------------------------------------------
// Kernel 3b: fold 2048 per-block (min,max) pairs into minmax[0..1]. 1 block.
__global__ __launch_bounds__(1024) void reduce_minmax(
    const float* __restrict__ bmin, const float* __restrict__ bmax,
    unsigned int* __restrict__ minmax)
{
    int tid = threadIdx.x;
    float mn = fminf(bmin[tid], bmin[tid + 1024]);
    float mx = fmaxf(bmax[tid], bmax[tid + 1024]);
    #pragma unroll
    for (int off = 32; off >= 1; off >>= 1) {
        mn = fminf(mn, __shfl_xor(mn, off));
        mx = fmaxf(mx, __shfl_xor(mx, off));
    }
    __shared__ float smn[16], smx[16];
    int wv = tid >> 6;
    if ((tid & 63) == 0) { smn[wv] = mn; smx[wv] = mx; }
    __syncthreads();
    if (tid == 0) {
        float m = smn[0], M = smx[0];
        #pragma unroll
        for (int i = 1; i < 16; ++i) { m = fminf(m, smn[i]); M = fmaxf(M, smx[i]); }
        minmax[0] = __float_as_uint(m);
        minmax[1] = __float_as_uint(M);
    }
}

// ---------------------------------------------------------------------------
// Kernel 4: merge coarse+fine (stable rank sort of 96), final ray-march.
// (unchanged known-passing serial-cumprod version)
__global__ __launch_bounds__(256) void final_march(
    const float* __restrict__ depth_c, const float* __restrict__ sigma_c,
    const float* __restrict__ rgb_c,
    const float* __restrict__ depth_f, const float* __restrict__ sigma_f,
    const float* __restrict__ rgb_f,
    const unsigned int* __restrict__ minmax,
    float* __restrict__ out)
{
    __shared__ float dall[4][96];
    __shared__ float sall[4][96];
    __shared__ float dsrt[4][96];
    __shared__ float ssrt[4][96];
    __shared__ int   perm[4][96];
    __shared__ float al[4][96];

    int wid = threadIdx.x >> 6, lane = threadIdx.x & 63;
    int ray = blockIdx.x * 4 + wid;

    for (int j = lane; j < 96; j += 64) {
        float dv, sv;
        if (j < 48) { dv = depth_c[(size_t)ray*48 + j]; sv = sigma_c[(size_t)ray*48 + j]; }
        else        { dv = depth_f[(size_t)ray*48 + j-48]; sv = sigma_f[(size_t)ray*48 + j-48]; }
        dall[wid][j] = dv; sall[wid][j] = sv;
    }
    __syncthreads();
    for (int j = lane; j < 96; j += 64) {
        float dj = dall[wid][j];
        int rank = 0;
        for (int k = 0; k < 96; ++k) {
            float dk = dall[wid][k];
            rank += (dk < dj || (dk == dj && k < j)) ? 1 : 0;
        }
        dsrt[wid][rank] = dj;
        ssrt[wid][rank] = sall[wid][j];
        perm[wid][rank] = j;
    }
    __syncthreads();
    for (int i = lane; i < 95; i += 64) {
        float dlt = dsrt[wid][i+1] - dsrt[wid][i];
        float dens = softplusf(0.5f * (ssrt[wid][i] + ssrt[wid][i+1]) - 1.f);
        al[wid][i] = 1.f - expf(-dens * dlt);
    }
    __syncthreads();
    if (lane == 0) {
        float T = 1.f, wsum = 0.f, dsum = 0.f;
        for (int i = 0; i < 95; ++i) {
            float a = al[wid][i];
            float wloc = a * T;
            T *= 1.f - a + 1e-10f;
            al[wid][i] = wloc;
            wsum += wloc;
            dsum += wloc * 0.5f * (dsrt[wid][i] + dsrt[wid][i+1]);
        }
        float depth = dsum / wsum;
        if (isnan(depth)) depth = INFINITY;
        float gmn = __uint_as_float(minmax[0]);
        float gmx = __uint_as_float(minmax[1]);
        depth = fminf(fmaxf(depth, gmn), gmx);
        out[262144 + ray] = depth;
        out[270336 + ray] = wsum;
        out[278528 + ray] = T;
    }
    __syncthreads();
    int k = lane & 31, half = lane >> 5;
    int i0 = half * 48, i1 = half ? 95 : 48;
    const float* rc = rgb_c + (size_t)ray * 48 * 32;
    const float* rf = rgb_f + (size_t)ray * 48 * 32;
    float acc = 0.f;
    int j0 = perm[wid][i0];
    float cur = (j0 < 48) ? rc[j0*32 + k] : rf[(j0-48)*32 + k];
    for (int i = i0; i < i1; ++i) {
        int jn = perm[wid][i+1];
        float nxt = (jn < 48) ? rc[jn*32 + k] : rf[(jn-48)*32 + k];
        acc += al[wid][i] * (cur + nxt);
        cur = nxt;
    }
    acc *= 0.5f;
    acc += __shfl_xor(acc, 32);
    if (half == 0) out[(size_t)ray * 32 + k] = acc * 2.f - 1.f;
}

// ---------------------------------------------------------------------------
extern "C" void kernel_launch(void* const* d_in, const int* in_sizes, int n_in,
                              void* d_out, int out_size, void* d_ws, size_t ws_size,
                              hipStream_t stream) {
    const float* planes      = (const float*)d_in[0];
    const float* origins     = (const float*)d_in[1];
    const float* dirs        = (const float*)d_in[2];
    const float* w1          = (const float*)d_in[3];
    const float* b1          = (const float*)d_in[4];
    const float* w2          = (const float*)d_in[5];
    const float* b2          = (const float*)d_in[6];
    const float* noise_strat = (const float*)d_in[7];
    const float* noise_imp   = (const float*)d_in[8];
    float* out = (float*)d_out;
    float* ws  = (float*)d_ws;

    unsigned short* planes_bf = (unsigned short*)(ws + OFF_PLANES2);
    float* depth_c = ws + OFF_DEPTH_C;
    float* sigma_c = ws + OFF_SIGMA_C;
    float* rgb_c   = ws + OFF_RGB_C;
    float* depth_f = ws + OFF_DEPTH_F;
    float* sigma_f = ws + OFF_SIGMA_F;
    float* rgb_f   = ws + OFF_RGB_F;
    unsigned int* minmax = (unsigned int*)(ws + OFF_MINMAX);
    float* w2t = ws + OFF_W2T;
    // per-block minmax scratch: staged in rgb_f (overwritten later by fine pass)
    float* bmin = rgb_f;
    float* bmax = rgb_f + 2048;

    precompute2<<<1536, 256, 0, stream>>>(planes, w2, planes_bf, w2t);
    sample_mlp<<<NSAMP/128, 256, 0, stream>>>(planes_bf, nullptr, noise_strat, depth_c,
                                              origins, dirs, w1, b1, w2t, b2,
                                              sigma_c, rgb_c, 1);
    importance_kernel<<<NRAY/4, 256, 0, stream>>>(depth_c, sigma_c, noise_imp,
                                                  depth_f, bmin, bmax);
    reduce_minmax<<<1, 1024, 0, stream>>>(bmin, bmax, minmax);
    sample_mlp<<<NSAMP/128, 256, 0, stream>>>(planes_bf, depth_f, nullptr, nullptr,
                                              origins, dirs, w1, b1, w2t, b2,
                                              sigma_f, rgb_f, 0);
    final_march<<<NRAY/4, 256, 0, stream>>>(depth_c, sigma_c, rgb_c,
                                            depth_f, sigma_f, rgb_f, minmax, out);
}

// Round 5
// 367.511 us; speedup vs baseline: 1.2001x; 1.1003x over previous
//
#include <hip/hip_runtime.h>
#include <math.h>

// Problem constants
#define BB 2
#define RR 4096
#define NRAY (BB*RR)            // 8192
#define SC 48
#define NSAMP (NRAY*SC)         // 393216
#define CF 32
#define HID 64
#define ODIM 33                 // 1 sigma + 32 rgb
#define PRES 256
#define PLANE_HW (PRES*PRES)    // 65536
#define RAY_START 0.1f
#define RAY_END 2.0f
#define DELTA ((RAY_END-RAY_START)/(SC-1))

// workspace layout (in floats)
#define OFF_PLANES2  ((size_t)0)
#define OFF_DEPTH_C  ((size_t)12582912)                 // 393216
#define OFF_SIGMA_C  (OFF_DEPTH_C + 393216)             // 393216
#define OFF_RGB_C    (OFF_SIGMA_C + 393216)             // 12582912
#define OFF_DEPTH_F  (OFF_RGB_C + 12582912)             // 393216
#define OFF_SIGMA_F  (OFF_DEPTH_F + 393216)             // 393216
#define OFF_RGB_F    (OFF_SIGMA_F + 393216)             // 12582912
#define OFF_MINMAX   (OFF_RGB_F + 12582912)             // 2 uints (+2 pad)
#define OFF_W2T      (OFF_MINMAX + 4)                   // 33*64 floats (w2 transposed)

typedef __attribute__((ext_vector_type(2))) float f2_t;

// packed fp32 FMA: acc.{x,y} += a.{x,y} * b.{x,y}  (one VOP3P inst = 2 FMA)
__device__ __forceinline__ void pk_fma_vv(f2_t& acc, f2_t a, f2_t b) {
    asm("v_pk_fma_f32 %0, %1, %2, %0" : "+v"(acc) : "v"(a), "v"(b));
}
// variant with the (single allowed) scalar operand: b must be wave-uniform
__device__ __forceinline__ void pk_fma_vs(f2_t& acc, f2_t a, f2_t b) {
    asm("v_pk_fma_f32 %0, %1, %2, %0" : "+v"(acc) : "v"(a), "s"(b));
}
// dword of 2 packed bf16 -> f2_t {lo, hi}
__device__ __forceinline__ f2_t bfpair(unsigned int u) {
    union { unsigned int i; float f; } lo, hi;
    lo.i = u << 16;
    hi.i = u & 0xffff0000u;
    f2_t r; r.x = lo.f; r.y = hi.f;
    return r;
}

__device__ __forceinline__ float softplusf(float x) {
    return fmaxf(x, 0.f) + __logf(1.f + __expf(-fabsf(x)));
}
__device__ __forceinline__ float sigact(float o) {
    float r = __builtin_amdgcn_rcpf(1.f + __expf(-o));
    return fmaf(1.002f, r, -0.001f);
}
__device__ __forceinline__ unsigned short f2bf(float f) {
    union { float f; unsigned int u; } v; v.f = f;
    unsigned int r = v.u + 0x7fffu + ((v.u >> 16) & 1u);   // RNE
    return (unsigned short)(r >> 16);
}
__device__ __forceinline__ unsigned int pack2(float lo, float hi) {
    return (unsigned int)f2bf(lo) | ((unsigned int)f2bf(hi) << 16);
}

// ---------------------------------------------------------------------------
// Kernel 1: planes_bf[bp][y][x][c] = bf16(planes[bp][c][y][x]).
// Pure transpose+convert. Also: w2t = w2^T.
__global__ __launch_bounds__(256) void precompute2(
    const float* __restrict__ planes, const float* __restrict__ w2,
    unsigned short* __restrict__ planes_bf, float* __restrict__ w2t)
{
    if (blockIdx.x == 0 && threadIdx.x < ODIM) {
        int k = threadIdx.x;
        for (int j = 0; j < HID; ++j) w2t[k * HID + j] = w2[j * ODIM + k];
    }
    int row = blockIdx.x;
    int bp = row >> 8, y = row & 255;
    int x = threadIdx.x;
    const float* src = planes + (size_t)bp * CF * PLANE_HW + (size_t)y * PRES + x;
    unsigned short* dst = planes_bf + ((size_t)bp * PLANE_HW + (size_t)(y << 8) + x) * CF;
    #pragma unroll
    for (int q = 0; q < 4; ++q) {
        uint4 u;
        u.x = pack2(src[(size_t)(q*8+0)*PLANE_HW], src[(size_t)(q*8+1)*PLANE_HW]);
        u.y = pack2(src[(size_t)(q*8+2)*PLANE_HW], src[(size_t)(q*8+3)*PLANE_HW]);
        u.z = pack2(src[(size_t)(q*8+4)*PLANE_HW], src[(size_t)(q*8+5)*PLANE_HW]);
        u.w = pack2(src[(size_t)(q*8+6)*PLANE_HW], src[(size_t)(q*8+7)*PLANE_HW]);
        ((uint4*)dst)[q] = u;
    }
}

// ---------------------------------------------------------------------------
// Kernel 2 (R17): quad-coalesced gather. R12 vs R16 showed duration tracks
// DISTINCT CACHE-LINE TOUCHES (24/sample in both -> identical 127 us), not
// request count or bytes. Here a quad of 4 adjacent lanes reads one 64B texel
// in ONE instruction (4x16B contiguous -> TA coalesces to a single line
// access): 12 touches/sample. Features staged via LDS [c][s] (2-way bank
// aliasing = free); GEMM phase keeps R16's proven wave-uniform-weight shape
// (h2[16], halfu SGPR offsets, LDS reused for o-partials).
__global__ __launch_bounds__(256, 3) void sample_mlp(
    const unsigned short* __restrict__ planes_bf,
    const float* __restrict__ depths_in,   // fine pass
    const float* __restrict__ noise,       // coarse pass
    float* __restrict__ depth_out,         // coarse pass
    const float* __restrict__ origins,
    const float* __restrict__ dirs,
    const float* __restrict__ w1,
    const float* __restrict__ b1,
    const float* __restrict__ w2t, const float* __restrict__ b2,
    float* __restrict__ sigma_out, float* __restrict__ rgb_out,
    int coarse)
{
    __shared__ __align__(16) char s_mem[17408];
    float (*s_feat)[130] = (float (*)[130])s_mem;        // [32][130] = 16640 B
    float (*s_part)[64][34] = (float (*)[64][34])s_mem;  // [2][64][34] = 17408 B (reused)

    int tid = threadIdx.x;

    // ---- gather phase: quad qg = tid>>2 handles samples 2qg, 2qg+1 ----
    {
        int qg = tid >> 2, sl = tid & 3;
        int s0 = blockIdx.x * 128 + 2 * qg;              // pair never straddles a ray (48 even)
        int ray = s0 / SC;
        int b = ray >> 12;

        float dep[2];
        if (coarse) {
            int sb = s0 - ray * SC;
            dep[0] = RAY_START + (float)sb * DELTA + noise[s0] * DELTA;
            dep[1] = RAY_START + (float)(sb + 1) * DELTA + noise[s0 + 1] * DELTA;
            if (sl == 0) { depth_out[s0] = dep[0]; depth_out[s0 + 1] = dep[1]; }
        } else {
            dep[0] = depths_in[s0];
            dep[1] = depths_in[s0 + 1];
        }

        float ox = origins[ray*3+0], oy = origins[ray*3+1], oz = origins[ray*3+2];
        float dx = dirs[ray*3+0],    dy = dirs[ray*3+1],    dz = dirs[ray*3+2];

        f2_t fa[2][4];
        #pragma unroll
        for (int k = 0; k < 2; ++k)
            #pragma unroll
            for (int j = 0; j < 4; ++j) fa[k][j] = (f2_t){0.f, 0.f};

        #pragma unroll
        for (int k = 0; k < 2; ++k) {
            float cx = (ox + dep[k]*dx) * 0.5f;
            float cy = (oy + dep[k]*dy) * 0.5f;
            float cz = (oz + dep[k]*dz) * 0.5f;
            #pragma unroll
            for (int p = 0; p < 3; ++p) {
                float gx = (p == 0) ? cx : (p == 1) ? cy : cz;
                float gy = (p == 0) ? cy : (p == 1) ? cz : cx;
                float x = fmaf(gx, 128.f, 127.5f);
                float y = fmaf(gy, 128.f, 127.5f);
                float x0f = floorf(x), y0f = floorf(y);
                float wx1 = x - x0f, wy1 = y - y0f;
                int x0 = (int)x0f, y0 = (int)y0f;
                const unsigned short* pb = planes_bf + (size_t)(b*3 + p) * PLANE_HW * CF;
                #pragma unroll
                for (int cyi = 0; cyi < 2; ++cyi) {
                    #pragma unroll
                    for (int cxi = 0; cxi < 2; ++cxi) {
                        int xi = x0 + cxi, yi = y0 + cyi;
                        float wgt = ((cyi ? wy1 : 1.f - wy1) * (cxi ? wx1 : 1.f - wx1)) * (1.f/3.f);
                        if (xi < 0 || xi > 255 || yi < 0 || yi > 255) wgt = 0.f;
                        int xc = min(max(xi, 0), 255), yc = min(max(yi, 0), 255);
                        const uint4* tp = (const uint4*)(pb + (size_t)((yc << 8) + xc) * CF);
                        uint4 v = tp[sl];                // quad covers the 64B texel in 1 inst
                        f2_t wp2; wp2.x = wgt; wp2.y = wgt;
                        pk_fma_vv(fa[k][0], bfpair(v.x), wp2);
                        pk_fma_vv(fa[k][1], bfpair(v.y), wp2);
                        pk_fma_vv(fa[k][2], bfpair(v.z), wp2);
                        pk_fma_vv(fa[k][3], bfpair(v.w), wp2);
                    }
                }
            }
        }

        // stash: lane owns channels [8sl, 8sl+8) for its 2 samples
        #pragma unroll
        for (int k = 0; k < 2; ++k)
            #pragma unroll
            for (int j = 0; j < 4; ++j) {
                s_feat[8*sl + 2*j    ][2*qg + k] = fa[k][j].x;
                s_feat[8*sl + 2*j + 1][2*qg + k] = fa[k][j].y;
            }
    }
    __syncthreads();

    // ---- GEMM phase: R16 mapping (wave pair splits hidden dim) ----
    int lane = tid & 63;
    int wv = tid >> 6;
    int halfu = __builtin_amdgcn_readfirstlane(wv & 1);   // SGPR: keeps weight loads scalar
    int pairu = __builtin_amdgcn_readfirstlane(wv >> 1);
    int ls = pairu * 64 + lane;                           // local sample 0..127
    int sample = blockIdx.x * 128 + ls;

    f2_t h2[16];
    const f2_t* b1p = (const f2_t*)(b1 + halfu * 32);
    #pragma unroll
    for (int j = 0; j < 16; ++j) h2[j] = b1p[j];

    #pragma unroll
    for (int c = 0; c < CF; ++c) {
        float fc = s_feat[c][ls];
        f2_t fc2; fc2.x = fc; fc2.y = fc;
        const f2_t* wp = (const f2_t*)(w1 + c * HID + halfu * 32);
        #pragma unroll
        for (int j = 0; j < 16; ++j) pk_fma_vs(h2[j], fc2, wp[j]);
    }
    #pragma unroll
    for (int j = 0; j < 16; ++j) {
        h2[j].x = softplusf(h2[j].x);
        h2[j].y = softplusf(h2[j].y);
    }

    // partial GEMM2 over own 32 hidden channels; w2t row halves via SGPR offset.
    float o[ODIM + 1];   // pad to 34 for f2 LDS traffic
    const f2_t* wbase = (const f2_t*)(w2t + halfu * 32);
    #pragma unroll
    for (int k = 0; k < ODIM; ++k) {
        const f2_t* wp = wbase + k * (HID/2);
        f2_t acc = (f2_t){0.f, 0.f};
        #pragma unroll
        for (int j = 0; j < 16; ++j) pk_fma_vs(acc, h2[j], wp[j]);
        o[k] = acc.x + acc.y;
    }
    o[ODIM] = 0.f;

    __syncthreads();   // all s_feat reads done; s_mem reused for o-partials
    if (halfu) {
        f2_t* dstp = (f2_t*)&s_part[pairu][lane][0];
        #pragma unroll
        for (int j = 0; j < 17; ++j) {
            f2_t v; v.x = o[2*j]; v.y = o[2*j+1];
            dstp[j] = v;
        }
    }
    __syncthreads();
    if (!halfu) {
        const f2_t* srcp = (const f2_t*)&s_part[pairu][lane][0];
        #pragma unroll
        for (int j = 0; j < 17; ++j) {
            f2_t v = srcp[j];
            o[2*j]   += v.x;
            o[2*j+1] += v.y;
        }
        #pragma unroll
        for (int k = 0; k < ODIM; ++k) o[k] += b2[k];

        sigma_out[sample] = o[0];
        float4* ro = (float4*)(rgb_out + (size_t)sample * 32);
        #pragma unroll
        for (int q = 0; q < 8; ++q) {
            float4 v;
            v.x = sigact(o[1 + q*4 + 0]);
            v.y = sigact(o[1 + q*4 + 1]);
            v.z = sigact(o[1 + q*4 + 2]);
            v.w = sigact(o[1 + q*4 + 3]);
            ro[q] = v;
        }
    }
}

// ---------------------------------------------------------------------------
// Kernel 3: importance sampling, one wave per ray; block-level minmax to
// scratch (bmin/bmax staged in rgb_f, overwritten later by the fine pass).
__global__ __launch_bounds__(256) void importance_kernel(
    const float* __restrict__ depth_c, const float* __restrict__ sigma_c,
    const float* __restrict__ noise_imp, float* __restrict__ depth_f,
    float* __restrict__ bmin, float* __restrict__ bmax)
{
    __shared__ float s_cdf[4][46];
    __shared__ float s_bins[4][47];
    __shared__ float s_red[8];
    int wave = threadIdx.x >> 6, lane = threadIdx.x & 63;
    int ray = blockIdx.x * 4 + wave;

    const float* d  = depth_c + (size_t)ray * SC;
    const float* sg = sigma_c + (size_t)ray * SC;
    float dval = (lane < SC) ? d[lane] : 0.f;
    float sval = (lane < SC) ? sg[lane] : 0.f;
    float dnext = __shfl_down(dval, 1);
    float snext = __shfl_down(sval, 1);

    float a = 0.f;
    if (lane < SC-1) {
        float dens = softplusf(0.5f * (sval + snext) - 1.f);
        a = 1.f - expf(-dens * (dnext - dval));
    }
    float f = (lane < SC-1) ? (1.f - a + 1e-10f) : 1.f;
    float incl = f;
    #pragma unroll
    for (int off = 1; off < 64; off <<= 1) {
        float t = __shfl_up(incl, off);
        if (lane >= off) incl *= t;
    }
    float T = (lane == 0) ? 1.f : __shfl_up(incl, 1);
    float w = a * T;
    float wm1 = __shfl_up(w, 1);
    float wp1 = __shfl_down(w, 1);
    float wn = 0.5f * (fmaxf(wm1, w) + fmaxf(w, wp1)) + 0.01f + 1e-5f;
    float g = (lane >= 1 && lane <= 45) ? wn : 0.f;
    float incl2 = g;
    #pragma unroll
    for (int off = 1; off < 64; off <<= 1) {
        float t = __shfl_up(incl2, off);
        if (lane >= off) incl2 += t;
    }
    float sum = __shfl(incl2, 45);
    if (lane == 0) s_cdf[wave][0] = 0.f;
    else if (lane <= 45) s_cdf[wave][lane] = incl2 / sum;
    if (lane < SC-1) s_bins[wave][lane] = 0.5f * (dval + dnext);
    __syncthreads();

    float fmn = 1e30f, fmx = -1e30f;
    if (lane < SC) {
        float u = noise_imp[(size_t)ray * SC + lane];
        int inds = 0;
        #pragma unroll
        for (int t = 0; t < 46; ++t) inds += (s_cdf[wave][t] <= u) ? 1 : 0;
        int below = max(inds - 1, 0), above = min(inds, 45);
        float cb = s_cdf[wave][below], ca = s_cdf[wave][above];
        float bb = s_bins[wave][below], ba = s_bins[wave][above];
        float den = (ca - cb < 1e-5f) ? 1.f : (ca - cb);
        float s = bb + (u - cb) / den * (ba - bb);
        depth_f[(size_t)ray * SC + lane] = s;
        fmn = s; fmx = s;
    }
    float d0 = __shfl(dval, 0), dlast = __shfl(dval, SC-1);
    fmn = fminf(fmn, d0); fmx = fmaxf(fmx, dlast);
    #pragma unroll
    for (int off = 32; off >= 1; off >>= 1) {
        fmn = fminf(fmn, __shfl_xor(fmn, off));
        fmx = fmaxf(fmx, __shfl_xor(fmx, off));
    }
    if (lane == 0) { s_red[wave] = fmn; s_red[4 + wave] = fmx; }
    __syncthreads();
    if (threadIdx.x == 0) {
        bmin[blockIdx.x] = fminf(fminf(s_red[0], s_red[1]), fminf(s_red[2], s_red[3]));
        bmax[blockIdx.x] = fmaxf(fmaxf(s_red[4], s_red[5]), fmaxf(s_red[6], s_red[7]));
    }
}

// ---------------------------------------------------------------------------
// Kernel 3b: fold 2048 per-block (min,max) pairs into minmax[0..1]. 1 block.
__global__ __launch_bounds__(1024) void reduce_minmax(
    const float* __restrict__ bmin, const float* __restrict__ bmax,
    unsigned int* __restrict__ minmax)
{
    int tid = threadIdx.x;
    float mn = fminf(bmin[tid], bmin[tid + 1024]);
    float mx = fmaxf(bmax[tid], bmax[tid + 1024]);
    #pragma unroll
    for (int off = 32; off >= 1; off >>= 1) {
        mn = fminf(mn, __shfl_xor(mn, off));
        mx = fmaxf(mx, __shfl_xor(mx, off));
    }
    __shared__ float smn[16], smx[16];
    int wv = tid >> 6;
    if ((tid & 63) == 0) { smn[wv] = mn; smx[wv] = mx; }
    __syncthreads();
    if (tid == 0) {
        float m = smn[0], M = smx[0];
        #pragma unroll
        for (int i = 1; i < 16; ++i) { m = fminf(m, smn[i]); M = fmaxf(M, smx[i]); }
        minmax[0] = __float_as_uint(m);
        minmax[1] = __float_as_uint(M);
    }
}

// ---------------------------------------------------------------------------
// Kernel 4: merge coarse+fine (stable rank sort of 96), final ray-march.
// (unchanged known-passing serial-cumprod version)
__global__ __launch_bounds__(256) void final_march(
    const float* __restrict__ depth_c, const float* __restrict__ sigma_c,
    const float* __restrict__ rgb_c,
    const float* __restrict__ depth_f, const float* __restrict__ sigma_f,
    const float* __restrict__ rgb_f,
    const unsigned int* __restrict__ minmax,
    float* __restrict__ out)
{
    __shared__ float dall[4][96];
    __shared__ float sall[4][96];
    __shared__ float dsrt[4][96];
    __shared__ float ssrt[4][96];
    __shared__ int   perm[4][96];
    __shared__ float al[4][96];

    int wid = threadIdx.x >> 6, lane = threadIdx.x & 63;
    int ray = blockIdx.x * 4 + wid;

    for (int j = lane; j < 96; j += 64) {
        float dv, sv;
        if (j < 48) { dv = depth_c[(size_t)ray*48 + j]; sv = sigma_c[(size_t)ray*48 + j]; }
        else        { dv = depth_f[(size_t)ray*48 + j-48]; sv = sigma_f[(size_t)ray*48 + j-48]; }
        dall[wid][j] = dv; sall[wid][j] = sv;
    }
    __syncthreads();
    for (int j = lane; j < 96; j += 64) {
        float dj = dall[wid][j];
        int rank = 0;
        for (int k = 0; k < 96; ++k) {
            float dk = dall[wid][k];
            rank += (dk < dj || (dk == dj && k < j)) ? 1 : 0;
        }
        dsrt[wid][rank] = dj;
        ssrt[wid][rank] = sall[wid][j];
        perm[wid][rank] = j;
    }
    __syncthreads();
    for (int i = lane; i < 95; i += 64) {
        float dlt = dsrt[wid][i+1] - dsrt[wid][i];
        float dens = softplusf(0.5f * (ssrt[wid][i] + ssrt[wid][i+1]) - 1.f);
        al[wid][i] = 1.f - expf(-dens * dlt);
    }
    __syncthreads();
    if (lane == 0) {
        float T = 1.f, wsum = 0.f, dsum = 0.f;
        for (int i = 0; i < 95; ++i) {
            float a = al[wid][i];
            float wloc = a * T;
            T *= 1.f - a + 1e-10f;
            al[wid][i] = wloc;
            wsum += wloc;
            dsum += wloc * 0.5f * (dsrt[wid][i] + dsrt[wid][i+1]);
        }
        float depth = dsum / wsum;
        if (isnan(depth)) depth = INFINITY;
        float gmn = __uint_as_float(minmax[0]);
        float gmx = __uint_as_float(minmax[1]);
        depth = fminf(fmaxf(depth, gmn), gmx);
        out[262144 + ray] = depth;
        out[270336 + ray] = wsum;
        out[278528 + ray] = T;
    }
    __syncthreads();
    int k = lane & 31, half = lane >> 5;
    int i0 = half * 48, i1 = half ? 95 : 48;
    const float* rc = rgb_c + (size_t)ray * 48 * 32;
    const float* rf = rgb_f + (size_t)ray * 48 * 32;
    float acc = 0.f;
    int j0 = perm[wid][i0];
    float cur = (j0 < 48) ? rc[j0*32 + k] : rf[(j0-48)*32 + k];
    for (int i = i0; i < i1; ++i) {
        int jn = perm[wid][i+1];
        float nxt = (jn < 48) ? rc[jn*32 + k] : rf[(jn-48)*32 + k];
        acc += al[wid][i] * (cur + nxt);
        cur = nxt;
    }
    acc *= 0.5f;
    acc += __shfl_xor(acc, 32);
    if (half == 0) out[(size_t)ray * 32 + k] = acc * 2.f - 1.f;
}

// ---------------------------------------------------------------------------
extern "C" void kernel_launch(void* const* d_in, const int* in_sizes, int n_in,
                              void* d_out, int out_size, void* d_ws, size_t ws_size,
                              hipStream_t stream) {
    const float* planes      = (const float*)d_in[0];
    const float* origins     = (const float*)d_in[1];
    const float* dirs        = (const float*)d_in[2];
    const float* w1          = (const float*)d_in[3];
    const float* b1          = (const float*)d_in[4];
    const float* w2          = (const float*)d_in[5];
    const float* b2          = (const float*)d_in[6];
    const float* noise_strat = (const float*)d_in[7];
    const float* noise_imp   = (const float*)d_in[8];
    float* out = (float*)d_out;
    float* ws  = (float*)d_ws;

    unsigned short* planes_bf = (unsigned short*)(ws + OFF_PLANES2);
    float* depth_c = ws + OFF_DEPTH_C;
    float* sigma_c = ws + OFF_SIGMA_C;
    float* rgb_c   = ws + OFF_RGB_C;
    float* depth_f = ws + OFF_DEPTH_F;
    float* sigma_f = ws + OFF_SIGMA_F;
    float* rgb_f   = ws + OFF_RGB_F;
    unsigned int* minmax = (unsigned int*)(ws + OFF_MINMAX);
    float* w2t = ws + OFF_W2T;
    // per-block minmax scratch: staged in rgb_f (overwritten later by fine pass)
    float* bmin = rgb_f;
    float* bmax = rgb_f + 2048;

    precompute2<<<1536, 256, 0, stream>>>(planes, w2, planes_bf, w2t);
    sample_mlp<<<NSAMP/128, 256, 0, stream>>>(planes_bf, nullptr, noise_strat, depth_c,
                                              origins, dirs, w1, b1, w2t, b2,
                                              sigma_c, rgb_c, 1);
    importance_kernel<<<NRAY/4, 256, 0, stream>>>(depth_c, sigma_c, noise_imp,
                                                  depth_f, bmin, bmax);
    reduce_minmax<<<1, 1024, 0, stream>>>(bmin, bmax, minmax);
    sample_mlp<<<NSAMP/128, 256, 0, stream>>>(planes_bf, depth_f, nullptr, nullptr,
                                              origins, dirs, w1, b1, w2t, b2,
                                              sigma_f, rgb_f, 0);
    final_march<<<NRAY/4, 256, 0, stream>>>(depth_c, sigma_c, rgb_c,
                                            depth_f, sigma_f, rgb_f, minmax, out);
}